// Round 11
// baseline (390.818 us; speedup 1.0000x reference)
//
#include <hip/hip_runtime.h>
#include <hip/hip_bf16.h>

#define FEAT 128
#define NRELS 8
#define KTOT 1024          // NRELS * FEAT
#define BN 16              // dst nodes per aggemm block (32 -> 16: 4 blocks/CU)
#define ECAP 192           // slab capacity per 16-node bucket (avg ~96)
#define CPAD 16            // cursor padding: one int per 64B line

typedef __bf16 bf16_t;
typedef __bf16 bf16x2_t __attribute__((ext_vector_type(2)));
typedef __bf16 bf16x4_t __attribute__((ext_vector_type(4)));
typedef __bf16 bf16x8_t __attribute__((ext_vector_type(8)));
typedef float f32x4 __attribute__((ext_vector_type(4)));

struct __align__(8) PackedEdge { int row; float scale; };
// row = (src<<7) | (local<<3) | rel ; key = row & 127 ; src = row >> 7

static inline size_t align256(size_t x) { return (x + 255) & ~(size_t)255; }

// ---------------------------------------------------------------------------
// Prep: wt2 convert (OUTPUT-driven: coalesced writes; strided reads hit L2,
// w = 8MB L2-resident) + cursor/ovfcnt zero + per-node {h->hb bf16, gate}.
__global__ __launch_bounds__(256) void k_prep(
    const float* __restrict__ h, const float* __restrict__ gwt,
    const float* __restrict__ w, float* __restrict__ sg,
    bf16_t* __restrict__ hb, bf16_t* __restrict__ wt2,
    int* __restrict__ cur, int N, int nbk) {
    const int t = threadIdx.x;
    const int gid = blockIdx.x * 256 + t;
    const int nthreads = gridDim.x * 256;
    for (int i = gid; i < NRELS * FEAT * FEAT; i += nthreads) {
        int f = i >> 10;            // wt2 row (output feat)
        int k = i & 1023;           // k = r*128 + d
        int r = k >> 7;
        int d = k & 127;
        wt2[i] = (bf16_t)w[(r << 14) + (d << 7) + f];
    }
    for (int i = gid; i < nbk * CPAD + 1; i += nthreads) cur[i] = 0;  // + ovfcnt

    const int gw_id = gid >> 6;
    const int nwaves = nthreads >> 6;
    const int lane = t & 63;
    for (int node = gw_id; node < N; node += nwaves) {
        float2 hv2 = *reinterpret_cast<const float2*>(h + (size_t)node * FEAT + lane * 2);
        bf16x2_t hc;
        hc.x = (bf16_t)hv2.x;
        hc.y = (bf16_t)hv2.y;
        *reinterpret_cast<bf16x2_t*>(hb + (size_t)node * FEAT + lane * 2) = hc;

        int r = lane >> 3;          // relation 0..7
        int g = lane & 7;           // d-group
        const float4* hp = reinterpret_cast<const float4*>(h + (size_t)node * FEAT + g * 16);
        const float4* wp = reinterpret_cast<const float4*>(gwt + r * FEAT + g * 16);
        float s = 0.f;
#pragma unroll
        for (int i = 0; i < 4; ++i) {
            float4 a = hp[i];
            float4 b = wp[i];
            s += a.x * b.x + a.y * b.y + a.z * b.z + a.w * b.w;
        }
        s += __shfl_xor(s, 1, 64);
        s += __shfl_xor(s, 2, 64);
        s += __shfl_xor(s, 4, 64);
        if (g == 0) sg[(size_t)node * NRELS + r] = 1.0f / (1.0f + __expf(-s));
    }
}

// ---------------------------------------------------------------------------
// Atomic-append fill into fixed-capacity per-bucket slabs (r8-verified scheme,
// bucket = 16 nodes).
__global__ void k_fills(const int* __restrict__ src, const int* __restrict__ dstv,
                        const int* __restrict__ rel, const float* __restrict__ nrm,
                        const float* __restrict__ sg, int* __restrict__ cur,
                        PackedEdge* __restrict__ slab, PackedEdge* __restrict__ ovfrec,
                        int* __restrict__ ovfbk, int* __restrict__ ovfcnt, int nedges) {
    int e = blockIdx.x * blockDim.x + threadIdx.x;
    if (e >= nedges) return;
    int d = dstv[e];
    int s = src[e];
    int r = rel[e];
    int bk = d >> 4;                 // BN = 16
    PackedEdge p;
    p.row = (s << 7) | ((d & 15) << 3) | r;
    p.scale = nrm[e] * sg[(size_t)s * NRELS + r];
    int pos = atomicAdd(&cur[bk * CPAD], 1);
    if (pos < ECAP) {
        slab[(size_t)bk * ECAP + pos] = p;
    } else {
        int op = atomicAdd(ovfcnt, 1);
        ovfrec[op] = p;
        ovfbk[op] = bk;
    }
}

// ---------------------------------------------------------------------------
// Fused sort + aggregate + GEMM + relu. Block = 512 threads (8 waves), 16 dst
// nodes. LDS: agg bf16 [16][2048B] XOR-swizzled (chunk^node) = 32KB + sort
// tables ~3KB => ~35KB -> 4 blocks/CU (the round-10 diagnosis: all pipes idle
// at 2 blocks/CU; occupancy doubles the phase-overlap opportunity).
// Phase A: one 32-lane group per node (8B/lane), round-8 edge order ->
// numerics bitwise-identical. Phase B: M=16, 1 A-read + 1 MFMA per iter,
// 4-deep bv ring from L2-hot wt2.
__global__ __launch_bounds__(512, 4) void k_aggemm(const bf16_t* __restrict__ hb,
                                                   const bf16_t* __restrict__ wt2,
                                                   const PackedEdge* __restrict__ slab,
                                                   const int* __restrict__ cur,
                                                   const PackedEdge* __restrict__ ovfrec,
                                                   const int* __restrict__ ovfbk,
                                                   const int* __restrict__ ovfcnt,
                                                   float* __restrict__ out, int nnodes) {
    __shared__ __align__(16) char lds_raw[BN * KTOT * sizeof(bf16_t)];   // 32 KiB
    __shared__ __align__(8) PackedEdge elist[ECAP];
    __shared__ int kcnt[128];
    __shared__ int kbase[129];
    __shared__ int kwork[128];
    float* cst = (float*)lds_raw;                 // aliased C-stage [16][132]
    const int t = threadIdx.x;
    const int nb0 = blockIdx.x * BN;
    const int lane = t & 63;
    const int wv = t >> 6;               // 0..7
    const int l15 = lane & 15;
    const int lhi = lane >> 4;

    // Phase-B bv preload (completes during sort/phase A)
    const bf16_t* bp = wt2 + (size_t)(wv * 16 + l15) * KTOT + lhi * 8;
    bf16x8_t bv0 = *reinterpret_cast<const bf16x8_t*>(bp);
    bf16x8_t bv1 = *reinterpret_cast<const bf16x8_t*>(bp + 32);
    bf16x8_t bv2 = *reinterpret_cast<const bf16x8_t*>(bp + 64);
    bf16x8_t bv3 = *reinterpret_cast<const bf16x8_t*>(bp + 96);

    // zero agg tile: 32KB / 512 threads = 4 x 16B each
    {
        f32x4 z = {0.f, 0.f, 0.f, 0.f};
#pragma unroll
        for (int i = 0; i < 4; ++i)
            reinterpret_cast<f32x4*>(lds_raw)[t + i * 512] = z;
    }

    const int cnt = cur[blockIdx.x * CPAD];
    const int nE = cnt < ECAP ? cnt : ECAP;
    if (t < 128) kcnt[t] = 0;
    __syncthreads();

    // coalesced slab load + count (128 keys: local*8+rel)
    PackedEdge myrec = {0, 0.f};
    if (t < nE) {
        myrec = slab[(size_t)blockIdx.x * ECAP + t];
        atomicAdd(&kcnt[myrec.row & 127], 1);
    }
    __syncthreads();

    // 64-lane shfl scan over 128 counters (wave 0, 2 keys/lane)
    if (t < 64) {
        int c0 = kcnt[t * 2], c1 = kcnt[t * 2 + 1];
        int tot = c0 + c1;
        int incl = tot;
#pragma unroll
        for (int off = 1; off < 64; off <<= 1) {
            int y = __shfl_up(incl, off, 64);
            if (t >= off) incl += y;
        }
        int excl = incl - tot;
        kbase[t * 2] = excl;          kwork[t * 2] = excl;
        kbase[t * 2 + 1] = excl + c0; kwork[t * 2 + 1] = excl + c0;
        if (t == 63) kbase[128] = excl + tot;   // = nE
    }
    __syncthreads();

    // scatter into sorted elist
    if (t < nE) elist[atomicAdd(&kwork[myrec.row & 127], 1)] = myrec;
    __syncthreads();

    // ---------------- Phase A: per-node aggregation (32 lanes/node) ----------------
    {
        const int node = t >> 5;             // local node 0..15
        const int c8 = t & 31;               // 8B sub-chunk 0..31 within 256B row
        const int sw = node;                 // XOR swizzle (node < 16)
        const int jbeg = kbase[node * 8];
        const int jend = kbase[node * 8 + 8];
        if (jbeg < jend) {
            float a[4];
#pragma unroll
            for (int i = 0; i < 4; ++i) a[i] = 0.f;
            int cur_r;

            auto ldrec = [&](int idx) {
                return elist[idx < jend ? idx : jend - 1];   // LDS broadcast
            };
            auto ldrow = [&](const PackedEdge& p) {
                return *reinterpret_cast<const bf16x4_t*>(
                    hb + ((size_t)(p.row >> 7) << 7) + c8 * 4);
            };
            auto flush = [&](int rr) {       // RMW add (zeros on first touch)
                int chunk = (rr * 16 + (c8 >> 1)) ^ sw;
                bf16_t* dp = reinterpret_cast<bf16_t*>(
                    lds_raw + (size_t)node * 2048 + chunk * 16 + (c8 & 1) * 8);
                bf16x4_t old = *reinterpret_cast<const bf16x4_t*>(dp);
                bf16x4_t o;
#pragma unroll
                for (int i = 0; i < 4; ++i) o[i] = (bf16_t)((float)old[i] + a[i]);
                *reinterpret_cast<bf16x4_t*>(dp) = o;
            };
            auto consume = [&](const PackedEdge& p, const bf16x4_t& v, int idx) {
                if (idx < jend) {
                    int r = p.row & 7;
                    if (r != cur_r) {        // group-uniform branch
                        flush(cur_r);
#pragma unroll
                        for (int i = 0; i < 4; ++i) a[i] = 0.f;
                        cur_r = r;
                    }
                    float s = p.scale;
#pragma unroll
                    for (int i = 0; i < 4; ++i) a[i] += (float)v[i] * s;
                }
            };

            PackedEdge p0 = ldrec(jbeg), p1 = ldrec(jbeg + 1);
            PackedEdge p2 = ldrec(jbeg + 2), p3 = ldrec(jbeg + 3);
            PackedEdge q0 = ldrec(jbeg + 4), q1 = ldrec(jbeg + 5);
            PackedEdge q2 = ldrec(jbeg + 6), q3 = ldrec(jbeg + 7);
            bf16x4_t v0 = ldrow(p0);
            bf16x4_t v1 = ldrow(p1);
            bf16x4_t v2 = ldrow(p2);
            bf16x4_t v3 = ldrow(p3);
            cur_r = p0.row & 7;

#pragma unroll 1
            for (int j = jbeg; j < jend; j += 4) {
                PackedEdge r0 = ldrec(j + 8), r1 = ldrec(j + 9);
                PackedEdge r2 = ldrec(j + 10), r3 = ldrec(j + 11);
                consume(p0, v0, j);
                consume(p1, v1, j + 1);
                consume(p2, v2, j + 2);
                consume(p3, v3, j + 3);
                v0 = ldrow(q0); v1 = ldrow(q1); v2 = ldrow(q2); v3 = ldrow(q3);
                p0 = q0; p1 = q1; p2 = q2; p3 = q3;
                q0 = r0; q1 = r1; q2 = r2; q3 = r3;
            }
            flush(cur_r);
        }

        // -------- rare overflow drain (normally novf == 0) --------
        int novf = *ovfcnt;
        if (novf > 0) {
#pragma unroll 1
            for (int i = 0; i < novf; ++i) {
                if (ovfbk[i] != blockIdx.x) continue;
                PackedEdge p = ovfrec[i];
                if (((p.row >> 3) & 15) != node) continue;
                bf16x4_t v = *reinterpret_cast<const bf16x4_t*>(
                    hb + ((size_t)(p.row >> 7) << 7) + c8 * 4);
                int chunk = ((p.row & 7) * 16 + (c8 >> 1)) ^ sw;
                bf16_t* dp = reinterpret_cast<bf16_t*>(
                    lds_raw + (size_t)node * 2048 + chunk * 16 + (c8 & 1) * 8);
                bf16x4_t old = *reinterpret_cast<const bf16x4_t*>(dp);
                bf16x4_t o;
#pragma unroll
                for (int k = 0; k < 4; ++k)
                    o[k] = (bf16_t)((float)old[k] + (float)v[k] * p.scale);
                *reinterpret_cast<bf16x4_t*>(dp) = o;
            }
        }
    }
    __syncthreads();

    // ---------------- Phase B: M=16 GEMM with 4-deep bv prefetch ----------------
    f32x4 acc0 = {0.f, 0.f, 0.f, 0.f};
    const char* a0p = lds_raw + (size_t)l15 * 2048;        // node rows 0..15
    const int swb = l15;                                   // matches write swizzle

#define PB_STEP(I, BV)                                                         \
    {                                                                          \
        int ks = ks0 + (I);                                                    \
        int coff = ((ks * 4 + lhi) ^ swb) << 4;                                \
        bf16x8_t av0 = *reinterpret_cast<const bf16x8_t*>(a0p + coff);         \
        bf16x8_t nxt = *reinterpret_cast<const bf16x8_t*>(                     \
            bp + (((ks + 4) & 31) * 32));                                      \
        acc0 = __builtin_amdgcn_mfma_f32_16x16x32_bf16(av0, BV, acc0, 0, 0, 0);\
        BV = nxt;                                                              \
    }

#pragma unroll 1
    for (int ks0 = 0; ks0 < 32; ks0 += 4) {
        PB_STEP(0, bv0)
        PB_STEP(1, bv1)
        PB_STEP(2, bv2)
        PB_STEP(3, bv3)
    }
#undef PB_STEP
    __syncthreads();   // all agg reads done; safe to overwrite with C

    // C layout: col(l15)=f within wave slice, row(lhi*4+i)=node (m89-verified)
    {
        int f = wv * 16 + l15;
#pragma unroll
        for (int i = 0; i < 4; ++i) {
            int n0 = lhi * 4 + i;
            cst[n0 * 132 + f] = acc0[i];
        }
    }
    __syncthreads();

    // relu + coalesced store: thread t -> node t>>5, feats (t&31)*4..+4
    {
        int node = t >> 5;
        int f0 = (t & 31) * 4;
        int gnode = nb0 + node;
        if (gnode < nnodes) {
            const float* cr = cst + node * 132 + f0;
            float4 o;
            o.x = fmaxf(cr[0], 0.f);
            o.y = fmaxf(cr[1], 0.f);
            o.z = fmaxf(cr[2], 0.f);
            o.w = fmaxf(cr[3], 0.f);
            *reinterpret_cast<float4*>(out + (size_t)gnode * FEAT + f0) = o;
        }
    }
}

// ---------------------------------------------------------------------------
extern "C" void kernel_launch(void* const* d_in, const int* in_sizes, int n_in,
                              void* d_out, int out_size, void* d_ws, size_t ws_size,
                              hipStream_t stream) {
    const float* h = (const float*)d_in[0];
    const float* w = (const float*)d_in[1];
    const float* gwt = (const float*)d_in[2];
    const float* nrm = (const float*)d_in[3];
    const int* src = (const int*)d_in[4];
    const int* dst = (const int*)d_in[5];
    const int* rel = (const int*)d_in[6];
    float* out = (float*)d_out;

    const int N = in_sizes[0] / FEAT;
    const int E = in_sizes[4];
    const int nbk = (N + BN - 1) / BN;

    char* ws = (char*)d_ws;
    const size_t wt2B = align256((size_t)FEAT * KTOT * sizeof(bf16_t));   // 256 KiB
    const size_t hbB  = align256((size_t)N * FEAT * sizeof(bf16_t));      // 25.6 MB
    const size_t sgB  = align256((size_t)N * NRELS * sizeof(float));      // 3.2 MB
    const size_t cuB  = align256(((size_t)nbk * CPAD + 1) * sizeof(int));
    const size_t slB  = align256((size_t)nbk * ECAP * sizeof(PackedEdge)); // 9.6 MB
    const size_t ovB  = align256((size_t)E * sizeof(PackedEdge));

    bf16_t* wt2 = (bf16_t*)ws;
    bf16_t* hb = (bf16_t*)(ws + wt2B);
    float* sg = (float*)(ws + wt2B + hbB);
    int* cur = (int*)(ws + wt2B + hbB + sgB);          // [nbk*CPAD] + ovfcnt
    int* ovfcnt = cur + (size_t)nbk * CPAD;
    PackedEdge* slab = (PackedEdge*)(ws + wt2B + hbB + sgB + cuB);
    PackedEdge* ovfrec = (PackedEdge*)(ws + wt2B + hbB + sgB + cuB + slB);
    int* ovfbk = (int*)(ws + wt2B + hbB + sgB + cuB + slB + ovB);

    k_prep<<<4096, 256, 0, stream>>>(h, gwt, w, sg, hb, wt2, cur, N, nbk);
    k_fills<<<(E + 255) / 256, 256, 0, stream>>>(src, dst, rel, nrm, sg, cur, slab,
                                                 ovfrec, ovfbk, ovfcnt, E);
    k_aggemm<<<nbk, 512, 0, stream>>>(hb, wt2, slab, cur, ovfrec, ovfbk, ovfcnt,
                                      out, N);
}

// Round 12
// 294.752 us; speedup vs baseline: 1.3259x; 1.3259x over previous
//
#include <hip/hip_runtime.h>
#include <hip/hip_bf16.h>

#define FEAT 128
#define NRELS 8
#define KTOT 1024          // NRELS * FEAT
#define BN 32              // dst nodes per aggemm block
#define SUBS 16            // sub-slabs per bucket (fills-atomic contention split)
#define SUBCAP 32          // capacity per sub-slab (avg ~12; P(>32) ~ 1e-6)
#define ECAPT (SUBS * SUBCAP)   // 512 slots per bucket
#define CPAD 16            // cursor padding: one int per 64B line

typedef __bf16 bf16_t;
typedef __bf16 bf16x2_t __attribute__((ext_vector_type(2)));
typedef __bf16 bf16x8_t __attribute__((ext_vector_type(8)));
typedef float f32x4 __attribute__((ext_vector_type(4)));

struct __align__(8) PackedEdge { int row; float scale; };
// row = (src<<8) | (local<<3) | rel ; key = row & 255 ; src = row >> 8

static inline size_t align256(size_t x) { return (x + 255) & ~(size_t)255; }

// ---------------------------------------------------------------------------
// Prep: wt2 convert (output-driven, coalesced writes) + cursor/ovfcnt zero +
// per-node {h->hb bf16, 8-rel sigmoid gate}. (r10-verified structure.)
__global__ __launch_bounds__(256) void k_prep(
    const float* __restrict__ h, const float* __restrict__ gwt,
    const float* __restrict__ w, float* __restrict__ sg,
    bf16_t* __restrict__ hb, bf16_t* __restrict__ wt2,
    int* __restrict__ cur, int N, int ncur) {
    const int t = threadIdx.x;
    const int gid = blockIdx.x * 256 + t;
    const int nthreads = gridDim.x * 256;
    for (int i = gid; i < NRELS * FEAT * FEAT; i += nthreads) {
        int f = i >> 10;            // wt2 row (output feat)
        int k = i & 1023;           // k = r*128 + d
        int r = k >> 7;
        int d = k & 127;
        wt2[i] = (bf16_t)w[(r << 14) + (d << 7) + f];
    }
    for (int i = gid; i < ncur; i += nthreads) cur[i] = 0;   // cursors + ovfcnt

    const int gw_id = gid >> 6;
    const int nwaves = nthreads >> 6;
    const int lane = t & 63;
    for (int node = gw_id; node < N; node += nwaves) {
        float2 hv2 = *reinterpret_cast<const float2*>(h + (size_t)node * FEAT + lane * 2);
        bf16x2_t hc;
        hc.x = (bf16_t)hv2.x;
        hc.y = (bf16_t)hv2.y;
        *reinterpret_cast<bf16x2_t*>(hb + (size_t)node * FEAT + lane * 2) = hc;

        int r = lane >> 3;          // relation 0..7
        int g = lane & 7;           // d-group
        const float4* hp = reinterpret_cast<const float4*>(h + (size_t)node * FEAT + g * 16);
        const float4* wp = reinterpret_cast<const float4*>(gwt + r * FEAT + g * 16);
        float s = 0.f;
#pragma unroll
        for (int i = 0; i < 4; ++i) {
            float4 a = hp[i];
            float4 b = wp[i];
            s += a.x * b.x + a.y * b.y + a.z * b.z + a.w * b.w;
        }
        s += __shfl_xor(s, 1, 64);
        s += __shfl_xor(s, 2, 64);
        s += __shfl_xor(s, 4, 64);
        if (g == 0) sg[(size_t)node * NRELS + r] = 1.0f / (1.0f + __expf(-s));
    }
}

// ---------------------------------------------------------------------------
// Atomic-append fill, 16 sub-slabs per bucket: sub = tid&15 decorrelates the
// cursor lines -> ~12 same-line atomics instead of 192 (the round-7/8 lesson,
// taken to its conclusion). Order within a bucket is arbitrary; the in-LDS
// counting sort in k_aggemm restores (node,rel) grouping.
__global__ void k_fills(const int* __restrict__ src, const int* __restrict__ dstv,
                        const int* __restrict__ rel, const float* __restrict__ nrm,
                        const float* __restrict__ sg, int* __restrict__ cur,
                        PackedEdge* __restrict__ slab, PackedEdge* __restrict__ ovfrec,
                        int* __restrict__ ovfbk, int* __restrict__ ovfcnt, int nedges) {
    int e = blockIdx.x * blockDim.x + threadIdx.x;
    if (e >= nedges) return;
    int d = dstv[e];
    int s = src[e];
    int r = rel[e];
    int bk = d >> 5;                       // BN = 32
    int sub = threadIdx.x & (SUBS - 1);
    PackedEdge p;
    p.row = (s << 8) | ((d & 31) << 3) | r;
    p.scale = nrm[e] * sg[(size_t)s * NRELS + r];
    int pos = atomicAdd(&cur[(bk * SUBS + sub) * CPAD], 1);
    if (pos < SUBCAP) {
        slab[(size_t)bk * ECAPT + sub * SUBCAP + pos] = p;
    } else {
        int op = atomicAdd(ovfcnt, 1);
        ovfrec[op] = p;
        ovfbk[op] = bk;
    }
}

// ---------------------------------------------------------------------------
// Fused sort + aggregate + GEMM + relu: round-10 body (137us, best measured).
// Only the slab load changed: 16 sub-segments are concatenated via a 16-lane
// prefix scan; count-sort makes segment order irrelevant.
__global__ __launch_bounds__(512, 4) void k_aggemm(const bf16_t* __restrict__ hb,
                                                   const bf16_t* __restrict__ wt2,
                                                   const PackedEdge* __restrict__ slab,
                                                   const int* __restrict__ cur,
                                                   const PackedEdge* __restrict__ ovfrec,
                                                   const int* __restrict__ ovfbk,
                                                   const int* __restrict__ ovfcnt,
                                                   float* __restrict__ out, int nnodes) {
    __shared__ __align__(16) char lds_raw[BN * KTOT * sizeof(bf16_t)];   // 64 KiB
    __shared__ __align__(8) PackedEdge elist[ECAPT];                     // 4 KiB
    __shared__ int kcnt[256];
    __shared__ int kbase[257];
    __shared__ int kwork[256];
    __shared__ int sbase[SUBS + 1];
    float* cst = (float*)lds_raw;                 // aliased C-stage [32][132]
    const int t = threadIdx.x;
    const int nb0 = blockIdx.x * BN;
    const int lane = t & 63;
    const int wv = t >> 6;               // 0..7
    const int l15 = lane & 15;
    const int lhi = lane >> 4;

    // Phase-B bv preload (completes during sort/phase A)
    const bf16_t* bp = wt2 + (size_t)(wv * 16 + l15) * KTOT + lhi * 8;
    bf16x8_t bv0 = *reinterpret_cast<const bf16x8_t*>(bp);
    bf16x8_t bv1 = *reinterpret_cast<const bf16x8_t*>(bp + 32);
    bf16x8_t bv2 = *reinterpret_cast<const bf16x8_t*>(bp + 64);
    bf16x8_t bv3 = *reinterpret_cast<const bf16x8_t*>(bp + 96);

    // zero agg tile
    {
        f32x4 z = {0.f, 0.f, 0.f, 0.f};
#pragma unroll
        for (int i = 0; i < 8; ++i)
            reinterpret_cast<f32x4*>(lds_raw)[t + i * 512] = z;
    }
    if (t < 256) kcnt[t] = 0;

    // sub-segment counts -> exclusive bases (16-lane shfl scan, wave 0)
    if (t < SUBS) {
        int c = cur[(blockIdx.x * SUBS + t) * CPAD];
        int cc = c < SUBCAP ? c : SUBCAP;
        int incl = cc;
#pragma unroll
        for (int off = 1; off < SUBS; off <<= 1) {
            int y = __shfl_up(incl, off, 64);
            if (t >= off) incl += y;
        }
        sbase[t + 1] = incl;
        if (t == 0) sbase[0] = 0;
    }
    __syncthreads();

    const int nE = sbase[SUBS];          // <= 512 = blockDim

    // per-thread record from the concatenated segments + key count
    PackedEdge myrec = {0, 0.f};
    if (t < nE) {
        int seg = 0;
#pragma unroll 1
        while (sbase[seg + 1] <= t) ++seg;
        myrec = slab[(size_t)blockIdx.x * ECAPT + seg * SUBCAP + (t - sbase[seg])];
        atomicAdd(&kcnt[myrec.row & 255], 1);
    }
    __syncthreads();

    // 64-lane shfl scan over 256 counters (wave 0)
    if (t < 64) {
        int c0 = kcnt[t * 4], c1 = kcnt[t * 4 + 1];
        int c2 = kcnt[t * 4 + 2], c3 = kcnt[t * 4 + 3];
        int tot = c0 + c1 + c2 + c3;
        int incl = tot;
#pragma unroll
        for (int off = 1; off < 64; off <<= 1) {
            int y = __shfl_up(incl, off, 64);
            if (t >= off) incl += y;
        }
        int excl = incl - tot;
        kbase[t * 4] = excl;               kwork[t * 4] = excl;
        kbase[t * 4 + 1] = excl + c0;      kwork[t * 4 + 1] = excl + c0;
        kbase[t * 4 + 2] = excl + c0 + c1; kwork[t * 4 + 2] = excl + c0 + c1;
        kbase[t * 4 + 3] = excl + c0 + c1 + c2;
        kwork[t * 4 + 3] = excl + c0 + c1 + c2;
        if (t == 63) kbase[256] = excl + tot;   // = nE
    }
    __syncthreads();

    // scatter into sorted elist
    if (t < nE) elist[atomicAdd(&kwork[myrec.row & 255], 1)] = myrec;
    __syncthreads();

    // ---------------- Phase A: 64-chain aggregation (8 lanes/chain) ----------------
    {
        const int g2 = t >> 3;                       // chain 0..63
        const int node = g2 >> 1;                    // local node 0..31
        const int cidx = ((g2 & 1) << 3) | (t & 7);  // 16B chunk 0..15 in row
        const int sw = node & 15;
        const int jbeg = kbase[node * 8];
        const int jend = kbase[node * 8 + 8];
        if (jbeg < jend) {
            float a[8];
#pragma unroll
            for (int i = 0; i < 8; ++i) a[i] = 0.f;
            int cur_r;

            auto ldrec = [&](int idx) {
                return elist[idx < jend ? idx : jend - 1];   // LDS broadcast
            };
            auto ldrow = [&](const PackedEdge& p) {
                return *reinterpret_cast<const bf16x8_t*>(
                    hb + ((size_t)(p.row >> 8) << 7) + cidx * 8);
            };
            auto flush = [&](int rr) {       // RMW add (zeros on first touch)
                int chunk = (rr * 16 + cidx) ^ sw;
                bf16_t* dp = reinterpret_cast<bf16_t*>(
                    lds_raw + (size_t)node * 2048 + chunk * 16);
                bf16x8_t old = *reinterpret_cast<const bf16x8_t*>(dp);
                bf16x8_t o;
#pragma unroll
                for (int i = 0; i < 8; ++i) o[i] = (bf16_t)((float)old[i] + a[i]);
                *reinterpret_cast<bf16x8_t*>(dp) = o;
            };
            auto consume = [&](const PackedEdge& p, const bf16x8_t& v, int idx) {
                if (idx < jend) {
                    int r = p.row & 7;
                    if (r != cur_r) {        // chain-uniform branch
                        flush(cur_r);
#pragma unroll
                        for (int i = 0; i < 8; ++i) a[i] = 0.f;
                        cur_r = r;
                    }
                    float s = p.scale;
#pragma unroll
                    for (int i = 0; i < 8; ++i) a[i] += (float)v[i] * s;
                }
            };

            PackedEdge p0 = ldrec(jbeg), p1 = ldrec(jbeg + 1);
            PackedEdge p2 = ldrec(jbeg + 2), p3 = ldrec(jbeg + 3);
            PackedEdge q0 = ldrec(jbeg + 4), q1 = ldrec(jbeg + 5);
            PackedEdge q2 = ldrec(jbeg + 6), q3 = ldrec(jbeg + 7);
            bf16x8_t v0 = ldrow(p0);
            bf16x8_t v1 = ldrow(p1);
            bf16x8_t v2 = ldrow(p2);
            bf16x8_t v3 = ldrow(p3);
            cur_r = p0.row & 7;

#pragma unroll 1
            for (int j = jbeg; j < jend; j += 4) {
                PackedEdge r0 = ldrec(j + 8), r1 = ldrec(j + 9);
                PackedEdge r2 = ldrec(j + 10), r3 = ldrec(j + 11);
                consume(p0, v0, j);
                consume(p1, v1, j + 1);
                consume(p2, v2, j + 2);
                consume(p3, v3, j + 3);
                v0 = ldrow(q0); v1 = ldrow(q1); v2 = ldrow(q2); v3 = ldrow(q3);
                p0 = q0; p1 = q1; p2 = q2; p3 = q3;
                q0 = r0; q1 = r1; q2 = r2; q3 = r3;
            }
            flush(cur_r);
        }

        // -------- rare overflow drain (normally novf == 0) --------
        int novf = *ovfcnt;
        if (novf > 0) {
#pragma unroll 1
            for (int i = 0; i < novf; ++i) {
                if (ovfbk[i] != blockIdx.x) continue;
                PackedEdge p = ovfrec[i];
                if (((p.row >> 3) & 31) != node) continue;
                bf16x8_t v = *reinterpret_cast<const bf16x8_t*>(
                    hb + ((size_t)(p.row >> 8) << 7) + cidx * 8);
                int chunk = ((p.row & 7) * 16 + cidx) ^ sw;
                bf16_t* dp = reinterpret_cast<bf16_t*>(
                    lds_raw + (size_t)node * 2048 + chunk * 16);
                bf16x8_t old = *reinterpret_cast<const bf16x8_t*>(dp);
                bf16x8_t o;
#pragma unroll
                for (int k = 0; k < 8; ++k)
                    o[k] = (bf16_t)((float)old[k] + (float)v[k] * p.scale);
                *reinterpret_cast<bf16x8_t*>(dp) = o;
            }
        }
    }
    __syncthreads();

    // ---------------- Phase B: GEMM with 4-deep bv prefetch ----------------
    f32x4 acc0 = {0.f, 0.f, 0.f, 0.f};
    f32x4 acc1 = {0.f, 0.f, 0.f, 0.f};
    const char* a0p = lds_raw + (size_t)l15 * 2048;        // node rows 0..15
    const char* a1p = a0p + 16 * 2048;                     // node rows 16..31
    const int swb = l15;                 // (16+l15)&15 == l15 : matches write

#define PB_STEP(I, BV)                                                         \
    {                                                                          \
        int ks = ks0 + (I);                                                    \
        int coff = ((ks * 4 + lhi) ^ swb) << 4;                                \
        bf16x8_t av0 = *reinterpret_cast<const bf16x8_t*>(a0p + coff);         \
        bf16x8_t av1 = *reinterpret_cast<const bf16x8_t*>(a1p + coff);         \
        bf16x8_t nxt = *reinterpret_cast<const bf16x8_t*>(                     \
            bp + (((ks + 4) & 31) * 32));                                      \
        acc0 = __builtin_amdgcn_mfma_f32_16x16x32_bf16(av0, BV, acc0, 0, 0, 0);\
        acc1 = __builtin_amdgcn_mfma_f32_16x16x32_bf16(av1, BV, acc1, 0, 0, 0);\
        BV = nxt;                                                              \
    }

#pragma unroll 1
    for (int ks0 = 0; ks0 < 32; ks0 += 4) {
        PB_STEP(0, bv0)
        PB_STEP(1, bv1)
        PB_STEP(2, bv2)
        PB_STEP(3, bv3)
    }
#undef PB_STEP
    __syncthreads();   // all agg reads done; safe to overwrite with C

    // C layout: col(l15)=f within wave slice, row(lhi*4+i)=node (m89-verified)
    {
        int f = wv * 16 + l15;
#pragma unroll
        for (int i = 0; i < 4; ++i) {
            int n0 = lhi * 4 + i;
            cst[n0 * 132 + f] = acc0[i];
            cst[(n0 + 16) * 132 + f] = acc1[i];
        }
    }
    __syncthreads();

    // relu + coalesced store: thread t -> node t>>4, feats (t&15)*8..+8
    {
        int node = t >> 4;
        int f0 = (t & 15) * 8;
        int gnode = nb0 + node;
        if (gnode < nnodes) {
            const float* cr = cst + node * 132 + f0;
            float4 o0, o1;
            o0.x = fmaxf(cr[0], 0.f); o0.y = fmaxf(cr[1], 0.f);
            o0.z = fmaxf(cr[2], 0.f); o0.w = fmaxf(cr[3], 0.f);
            o1.x = fmaxf(cr[4], 0.f); o1.y = fmaxf(cr[5], 0.f);
            o1.z = fmaxf(cr[6], 0.f); o1.w = fmaxf(cr[7], 0.f);
            float4* op = reinterpret_cast<float4*>(out + (size_t)gnode * FEAT + f0);
            op[0] = o0;
            op[1] = o1;
        }
    }
}

// ---------------------------------------------------------------------------
extern "C" void kernel_launch(void* const* d_in, const int* in_sizes, int n_in,
                              void* d_out, int out_size, void* d_ws, size_t ws_size,
                              hipStream_t stream) {
    const float* h = (const float*)d_in[0];
    const float* w = (const float*)d_in[1];
    const float* gwt = (const float*)d_in[2];
    const float* nrm = (const float*)d_in[3];
    const int* src = (const int*)d_in[4];
    const int* dst = (const int*)d_in[5];
    const int* rel = (const int*)d_in[6];
    float* out = (float*)d_out;

    const int N = in_sizes[0] / FEAT;
    const int E = in_sizes[4];
    const int nbk = (N + BN - 1) / BN;
    const int ncur = nbk * SUBS * CPAD + 1;           // cursors + ovfcnt

    char* ws = (char*)d_ws;
    const size_t wt2B = align256((size_t)FEAT * KTOT * sizeof(bf16_t));   // 256 KiB
    const size_t hbB  = align256((size_t)N * FEAT * sizeof(bf16_t));      // 25.6 MB
    const size_t sgB  = align256((size_t)N * NRELS * sizeof(float));      // 3.2 MB
    const size_t cuB  = align256((size_t)ncur * sizeof(int));             // 3.2 MB
    const size_t slB  = align256((size_t)nbk * ECAPT * sizeof(PackedEdge)); // 12.8 MB
    const size_t ovB  = align256((size_t)E * sizeof(PackedEdge));

    bf16_t* wt2 = (bf16_t*)ws;
    bf16_t* hb = (bf16_t*)(ws + wt2B);
    float* sg = (float*)(ws + wt2B + hbB);
    int* cur = (int*)(ws + wt2B + hbB + sgB);          // [nbk*SUBS*CPAD] + ovfcnt
    int* ovfcnt = cur + (size_t)nbk * SUBS * CPAD;
    PackedEdge* slab = (PackedEdge*)(ws + wt2B + hbB + sgB + cuB);
    PackedEdge* ovfrec = (PackedEdge*)(ws + wt2B + hbB + sgB + cuB + slB);
    int* ovfbk = (int*)(ws + wt2B + hbB + sgB + cuB + slB + ovB);

    k_prep<<<4096, 256, 0, stream>>>(h, gwt, w, sg, hb, wt2, cur, N, ncur);
    k_fills<<<(E + 255) / 256, 256, 0, stream>>>(src, dst, rel, nrm, sg, cur, slab,
                                                 ovfrec, ovfbk, ovfcnt, E);
    k_aggemm<<<nbk, 512, 0, stream>>>(hb, wt2, slab, cur, ovfrec, ovfbk, ovfcnt,
                                      out, N);
}